// Round 3
// baseline (657.071 us; speedup 1.0000x reference)
//
#include <hip/hip_runtime.h>

// ---------------------------------------------------------------------------
// DoshaGAT: 3-layer GAT. R7:
//  - Aggregates rebuilt as XCD-sliced kernels: feature dim split into 8
//    slices, slice = blockIdx%8 -> XCD affinity (round-robin dispatch).
//    h stored slice-major (8 compact subtables, N*64B / N*32B) so each XCD's
//    gather working set is 3.2MB / 1.6MB -> fits 4MiB L2. csr reads and
//    outputs are nontemporal to keep L2 reserved for the h slice.
//  - GEMM epilogues store h directly in slice-major layout.
//  - l3 fusion moved out of the layer-2 aggregate into l3_prep (o2 kept f32
//    in the retired h_bf1 region; no extra quantization).
// phys<->logical col mapping unchanged: within head block, phys q<->logical
// (q&(CF-1))*16 + q/CF.
// ---------------------------------------------------------------------------

#define WSZ 64

typedef short short8 __attribute__((ext_vector_type(8)));
typedef short short4v __attribute__((ext_vector_type(4)));
typedef float float4v __attribute__((ext_vector_type(4)));
typedef float f2v __attribute__((ext_vector_type(2)));

__device__ inline unsigned short f2bf(float f) {  // RNE f32->bf16
  unsigned u = __float_as_uint(f);
  u += 0x7FFFu + ((u >> 16) & 1u);
  return (unsigned short)(u >> 16);
}
__device__ inline float bf2f(unsigned short u) {
  return __uint_as_float(((unsigned)u) << 16);
}

// ---------------- CSR build ----------------

__global__ __launch_bounds__(256) void hist_kernel(const int* __restrict__ dst, int E,
                                                   int* __restrict__ deg) {
  int e = blockIdx.x * 256 + threadIdx.x;
  if (e < E) atomicAdd(&deg[dst[e]], 1);
}

__global__ __launch_bounds__(256) void block_sums_kernel(const int* __restrict__ deg, int n,
                                                         int* __restrict__ bsum) {
  __shared__ int sh[256];
  int t = threadIdx.x;
  int base = blockIdx.x * 1024 + t * 4;
  int v = 0;
#pragma unroll
  for (int j = 0; j < 4; ++j) {
    int idx = base + j;
    if (idx < n) v += deg[idx];
  }
  sh[t] = v;
  __syncthreads();
  for (int off = 128; off >= 1; off >>= 1) {
    if (t < off) sh[t] += sh[t + off];
    __syncthreads();
  }
  if (t == 0) bsum[blockIdx.x] = sh[0];
}

__global__ void tiny_scan_kernel(int* bsum, int nb) {
  if (threadIdx.x == 0 && blockIdx.x == 0) {
    int run = 0;
    for (int i = 0; i < nb; ++i) {
      int v = bsum[i];
      bsum[i] = run;
      run += v;
    }
  }
}

__global__ __launch_bounds__(256) void scan_write_kernel(const int* __restrict__ deg, int n,
                                                         const int* __restrict__ bbase,
                                                         int* __restrict__ row_start,
                                                         int* __restrict__ cursor) {
  __shared__ int sh[256];
  int t = threadIdx.x;
  int base = blockIdx.x * 1024 + t * 4;
  int v[4];
  int s = 0;
#pragma unroll
  for (int j = 0; j < 4; ++j) {
    int idx = base + j;
    v[j] = (idx < n) ? deg[idx] : 0;
    s += v[j];
  }
  sh[t] = s;
  __syncthreads();
  for (int off = 1; off < 256; off <<= 1) {
    int x = (t >= off) ? sh[t - off] : 0;
    __syncthreads();
    sh[t] += x;
    __syncthreads();
  }
  int excl = sh[t] - s + bbase[blockIdx.x];
#pragma unroll
  for (int j = 0; j < 4; ++j) {
    int idx = base + j;
    if (idx < n) {
      row_start[idx] = excl;
      cursor[idx] = excl;
    }
    excl += v[j];
  }
  if (blockIdx.x == gridDim.x - 1 && t == 255) row_start[n] = excl;  // == E
}

__global__ __launch_bounds__(256) void scatter_kernel(const int* __restrict__ src,
                                                      const int* __restrict__ dst, int E,
                                                      int* __restrict__ cursor,
                                                      int* __restrict__ csr_src) {
  int e = blockIdx.x * 256 + threadIdx.x;
  if (e < E) {
    int d = dst[e];
    int p = atomicAdd(&cursor[d], 1);
    csr_src[p] = src[e];
  }
}

// ---------------- weight conversion ----------------

// W1 [128][256] -> W1t [256][128] bf16
__global__ __launch_bounds__(256) void conv_w1t_kernel(const float* __restrict__ W1,
                                                       unsigned short* __restrict__ W1t) {
  int idx = blockIdx.x * 256 + threadIdx.x;  // 32768
  int n = idx >> 7, k = idx & 127;
  W1t[idx] = f2bf(W1[k * 256 + n]);
}

// W2 [256][128] -> W2t [128][256] bf16, K rows permuted to layer-1 phys layout
__global__ __launch_bounds__(256) void conv_w2t_kernel(const float* __restrict__ W2,
                                                       unsigned short* __restrict__ W2t) {
  int idx = blockIdx.x * 256 + threadIdx.x;  // 32768
  int n = idx >> 8, p = idx & 255;
  int kl = (p & ~63) | ((p & 3) << 4) | ((p >> 2) & 15);
  W2t[idx] = f2bf(W2[kl * 128 + n]);
}

// ---------------- bf16 MFMA GEMM + fused attn-coeff epilogue ----------------
// C[M,BN] = A[M,K] @ B[K,BN]. 64-row blocks, 256 threads, 4 waves (wave=head).
// AF32: A is f32, converted to bf16 during LDS staging.
// hout is written SLICE-MAJOR: 8 subtables of [M][BN/8] bf16; phys col p
// belongs to subtable p/(BN/8).

template <int K, int BN, bool AF32>
__global__ __launch_bounds__(256) void gemm_mfma(
    const void* __restrict__ Ap,            // [M][K] bf16 or f32
    const unsigned short* __restrict__ Bt,  // [BN][K] bf16 (pre-transposed)
    const float* __restrict__ a_s, const float* __restrict__ a_d,  // [BN] logical
    unsigned short* __restrict__ hout,      // slice-major output
    float* __restrict__ als, float* __restrict__ ald,  // [M][4]
    int M) {
  constexpr int CF = BN / 64;  // col frags per wave
  constexpr int SF = BN / 8;   // feats per slice (32 or 16)
  constexpr int PAD = 36;
  __shared__ unsigned short As[64][PAD];
  __shared__ unsigned short Bs[BN][PAD];
  const int t = threadIdx.x;
  const int w = t >> 6;
  const int lane = t & 63;
  const int c16 = lane & 15;
  const int q = lane >> 4;
  const int bm = blockIdx.x * 64;
  const int arow = t >> 2;      // 0..63
  const int akc = (t & 3) * 8;  // 0,8,16,24

  float4v acc[4][CF];
#pragma unroll
  for (int rf = 0; rf < 4; ++rf)
#pragma unroll
    for (int cf = 0; cf < CF; ++cf) acc[rf][cf] = float4v{0.f, 0.f, 0.f, 0.f};

  for (int k0 = 0; k0 < K; k0 += 32) {
    {  // stage A tile 64x32 (8 elems/thread)
      int gr = bm + arow;
      if constexpr (AF32) {
        const float* Af = (const float*)Ap + (size_t)gr * K + k0 + akc;
        float4 v0 = make_float4(0.f, 0.f, 0.f, 0.f), v1 = v0;
        if (gr < M) {
          v0 = *(const float4*)Af;
          v1 = *(const float4*)(Af + 4);
        }
        ushort4 u0, u1;
        u0.x = f2bf(v0.x); u0.y = f2bf(v0.y); u0.z = f2bf(v0.z); u0.w = f2bf(v0.w);
        u1.x = f2bf(v1.x); u1.y = f2bf(v1.y); u1.z = f2bf(v1.z); u1.w = f2bf(v1.w);
        *(ushort4*)&As[arow][akc] = u0;
        *(ushort4*)&As[arow][akc + 4] = u1;
      } else {
        uint4 v = make_uint4(0u, 0u, 0u, 0u);
        if (gr < M) v = *(const uint4*)((const unsigned short*)Ap + (size_t)gr * K + k0 + akc);
        *(uint2*)&As[arow][akc] = make_uint2(v.x, v.y);
        *(uint2*)&As[arow][akc + 4] = make_uint2(v.z, v.w);
      }
    }
#pragma unroll
    for (int h = 0; h < BN / 64; ++h) {  // stage B tile BNx32
      int n = (t >> 2) + h * 64;
      uint4 v = *(const uint4*)(Bt + (size_t)n * K + k0 + akc);
      *(uint2*)&Bs[n][akc] = make_uint2(v.x, v.y);
      *(uint2*)&Bs[n][akc + 4] = make_uint2(v.z, v.w);
    }
    __syncthreads();
    short8 af[4], bfr[CF];
#pragma unroll
    for (int rf = 0; rf < 4; ++rf) {
      short4v lo = *(short4v*)&As[rf * 16 + c16][q * 8];
      short4v hi = *(short4v*)&As[rf * 16 + c16][q * 8 + 4];
      af[rf] = __builtin_shufflevector(lo, hi, 0, 1, 2, 3, 4, 5, 6, 7);
    }
#pragma unroll
    for (int cf = 0; cf < CF; ++cf) {
      int n = w * (CF * 16) + cf * 16 + c16;
      short4v lo = *(short4v*)&Bs[n][q * 8];
      short4v hi = *(short4v*)&Bs[n][q * 8 + 4];
      bfr[cf] = __builtin_shufflevector(lo, hi, 0, 1, 2, 3, 4, 5, 6, 7);
    }
#pragma unroll
    for (int rf = 0; rf < 4; ++rf)
#pragma unroll
      for (int cf = 0; cf < CF; ++cf)
        acc[rf][cf] =
            __builtin_amdgcn_mfma_f32_16x16x32_bf16(af[rf], bfr[cf], acc[rf][cf], 0, 0, 0);
    __syncthreads();
  }

  float sasv[CF], sadv[CF];
#pragma unroll
  for (int cf = 0; cf < CF; ++cf) {
    int L = w * (CF * 16) + cf * 16 + c16;
    sasv[cf] = a_s[L];
    sadv[cf] = a_d[L];
  }
  // slice-major store base: subtable = w*2 + (c16>>3)
  const size_t sub = (size_t)(w * 2 + (c16 >> 3)) * (size_t)M * SF;
#pragma unroll
  for (int rf = 0; rf < 4; ++rf) {
#pragma unroll
    for (int r = 0; r < 4; ++r) {
      int n = bm + rf * 16 + q * 4 + r;
      float ps = 0.f, pd = 0.f;
      unsigned short us[CF];
#pragma unroll
      for (int cf = 0; cf < CF; ++cf) {
        float v = acc[rf][cf][r];
        us[cf] = f2bf(v);
        ps += v * sasv[cf];
        pd += v * sadv[cf];
      }
#pragma unroll
      for (int off = 1; off <= 8; off <<= 1) {
        ps += __shfl_xor(ps, off, 16);
        pd += __shfl_xor(pd, off, 16);
      }
      if (n < M) {
        if constexpr (CF == 4) {
          ushort4 u;
          u.x = us[0]; u.y = us[1]; u.z = us[2]; u.w = us[3];
          *(ushort4*)(hout + sub + (size_t)n * 32 + (c16 & 7) * 4) = u;
        } else {
          ushort2 u;
          u.x = us[0]; u.y = us[1];
          *(ushort2*)(hout + sub + (size_t)n * 16 + (c16 & 7) * 2) = u;
        }
        if (c16 == 0) {
          als[(size_t)n * 4 + w] = ps;
          ald[(size_t)n * 4 + w] = pd;
        }
      }
    }
  }
}

// ---------------- XCD-sliced GAT aggregation + bias + BN + ELU --------------
// slice = blockIdx%8 -> XCD affinity. Each wave: one (node, slice); lanes =
// EPG edge-groups x FP feature-pairs. Per-XCD gather working set = table/8
// (3.2MB / 1.6MB) -> L2-resident. csr nt-loaded, outputs nt-stored.
// D==256: writes o1 bf16 row-major (phys). D==128: writes o2 f32 row-major.

template <int D>
__global__ __launch_bounds__(256) void gat_agg_slice(
    const unsigned short* __restrict__ h_sl,  // 8 slice-major subtables
    const float* __restrict__ als, const float* __restrict__ ald,
    const int* __restrict__ row_start, const int* __restrict__ csr_src,
    const float* __restrict__ bias, const float* __restrict__ gamma,
    const float* __restrict__ beta, const float* __restrict__ bmean,
    const float* __restrict__ bvar,
    unsigned short* __restrict__ obf,  // D==256 out
    float* __restrict__ of32,          // D==128 out
    int n_nodes) {
  constexpr int SFEAT = (D == 256) ? 32 : 16;  // feats per slice
  constexpr int FP = SFEAT / 2;                // feature-pair lanes per edge
  constexpr int EPG = 64 / FP;                 // edges per iteration
  const int b = blockIdx.x;
  const int sl = b & 7;
  const int g = b >> 3;
  const int wid = threadIdx.x >> 6;
  const int lane = threadIdx.x & 63;
  const int f = lane & (FP - 1);
  const int eg = lane >> ((D == 256) ? 4 : 3);
  const int head = sl >> 1;
  const char* hsb = (const char*)(h_sl + (size_t)sl * (size_t)n_nodes * SFEAT);
  const char* ab = (const char*)als;

  for (int rep = 0; rep < 2; ++rep) {
    int n = __builtin_amdgcn_readfirstlane(g * 8 + wid + rep * 4);
    if (n >= n_nodes) continue;
    float aldv = ald[(size_t)n * 4 + head];
    int row = __builtin_amdgcn_readfirstlane(row_start[n]);
    int end = __builtin_amdgcn_readfirstlane(row_start[n + 1]);
    float acc0 = 0.f, acc1 = 0.f, ssum = 0.f;
    for (int i = row; i < end; i += EPG) {
      int idx = i + eg;
      idx = (idx < end) ? idx : (end - 1);
      int s = __builtin_nontemporal_load(&csr_src[idx]);
      float al = *(const float*)(ab + ((unsigned)s * 16u + (unsigned)(head * 4)));
      unsigned u = *(const unsigned*)(hsb + ((unsigned)s * (unsigned)(SFEAT * 2) +
                                             (unsigned)(f * 4)));
      float e = al + aldv;
      e = fmaxf(e, 0.2f * e);
      float ex = __expf(e);
      ex = (i + eg < end) ? ex : 0.f;
      ssum += ex;
      acc0 += ex * __uint_as_float(u << 16);
      acc1 += ex * __uint_as_float(u & 0xffff0000u);
    }
    // cross-edge-group reduction (groups partition edges; within-group lanes
    // hold identical ssum partials, per-f acc partials)
    if constexpr (EPG == 8) {
      ssum += __shfl_xor(ssum, 8, 64);
      acc0 += __shfl_xor(acc0, 8, 64);
      acc1 += __shfl_xor(acc1, 8, 64);
    }
    ssum += __shfl_xor(ssum, 16, 64);
    acc0 += __shfl_xor(acc0, 16, 64);
    acc1 += __shfl_xor(acc1, 16, 64);
    ssum += __shfl_xor(ssum, 32, 64);
    acc0 += __shfl_xor(acc0, 32, 64);
    acc1 += __shfl_xor(acc1, 32, 64);
    float inv = 1.f / (ssum + 1e-16f);
    // logical cols of phys p = sl*SFEAT + f*2 + {0,1}
    int l0, l1;
    if constexpr (D == 256) {
      l0 = head * 64 + ((f & 1) * 2 + 0) * 16 + (sl & 1) * 8 + (f >> 1);
      l1 = head * 64 + ((f & 1) * 2 + 1) * 16 + (sl & 1) * 8 + (f >> 1);
    } else {
      l0 = head * 32 + (sl & 1) * 8 + f;
      l1 = l0 + 16;
    }
    float o0 = acc0 * inv + bias[l0];
    o0 = (o0 - bmean[l0]) * rsqrtf(bvar[l0] + 1e-5f) * gamma[l0] + beta[l0];
    o0 = (o0 > 0.f) ? o0 : (__expf(o0) - 1.f);
    float o1v = acc1 * inv + bias[l1];
    o1v = (o1v - bmean[l1]) * rsqrtf(bvar[l1] + 1e-5f) * gamma[l1] + beta[l1];
    o1v = (o1v > 0.f) ? o1v : (__expf(o1v) - 1.f);
    if (eg == 0) {
      if constexpr (D == 256) {
        unsigned pk = (unsigned)f2bf(o0) | ((unsigned)f2bf(o1v) << 16);
        __builtin_nontemporal_store(
            pk, (unsigned*)(obf + (size_t)n * 256 + sl * 32 + f * 2));
      } else {
        f2v v2;
        v2.x = o0; v2.y = o1v;
        __builtin_nontemporal_store(
            v2, (f2v*)(of32 + (size_t)n * 128 + sl * 16 + f * 2));
      }
    }
  }
}

// ---------------- layer-3 prep: h3 = o2 @ W3, als3/ald3 ---------------------

__global__ __launch_bounds__(256) void l3_prep_kernel(
    const float* __restrict__ o2, const float* __restrict__ W3,
    const float* __restrict__ a3s, const float* __restrict__ a3d,
    float4* __restrict__ h3p, float* __restrict__ ald3, int n_nodes) {
  __shared__ float w3s[384];
  __shared__ float sa3[6];
  for (int i = threadIdx.x; i < 384; i += 256) w3s[i] = W3[i];
  if (threadIdx.x < 3) {
    sa3[threadIdx.x] = a3s[threadIdx.x];
    sa3[3 + threadIdx.x] = a3d[threadIdx.x];
  }
  __syncthreads();
  int wid = threadIdx.x >> 6, lane = threadIdx.x & 63;
  int n = blockIdx.x * 4 + wid;
  if (n >= n_nodes) return;
  f2v v = *(const f2v*)(o2 + (size_t)n * 128 + lane * 2);  // phys cols lane*2,+1
  int hd = lane >> 4;
  int k0l = hd * 32 + (lane & 15);  // logical k of phys col lane*2
  int k1l = k0l + 16;               // logical k of phys col lane*2+1
  float p0 = v.x * w3s[k0l * 3 + 0] + v.y * w3s[k1l * 3 + 0];
  float p1 = v.x * w3s[k0l * 3 + 1] + v.y * w3s[k1l * 3 + 1];
  float p2 = v.x * w3s[k0l * 3 + 2] + v.y * w3s[k1l * 3 + 2];
#pragma unroll
  for (int off = 32; off >= 1; off >>= 1) {
    p0 += __shfl_xor(p0, off, 64);
    p1 += __shfl_xor(p1, off, 64);
    p2 += __shfl_xor(p2, off, 64);
  }
  if (lane == 0) {
    float als3 = p0 * sa3[0] + p1 * sa3[1] + p2 * sa3[2];
    float ad3 = p0 * sa3[3] + p1 * sa3[4] + p2 * sa3[5];
    h3p[n] = make_float4(p0, p1, p2, als3);
    ald3[n] = ad3;
  }
}

// ---------------- layer 3 aggregation + log_softmax -------------------------

__global__ __launch_bounds__(256) void l3_agg_kernel(const float4* __restrict__ h3p,
                                                     const float* __restrict__ ald3,
                                                     const int* __restrict__ row_start,
                                                     const int* __restrict__ csr_src,
                                                     const float* __restrict__ b3,
                                                     float* __restrict__ out, int n_nodes) {
  int wid = threadIdx.x >> 6, lane = threadIdx.x & 63;
  int n = __builtin_amdgcn_readfirstlane(blockIdx.x * 4 + wid);
  if (n >= n_nodes) return;
  float aldv = ald3[n];
  int row = __builtin_amdgcn_readfirstlane(row_start[n]);
  int end = __builtin_amdgcn_readfirstlane(row_start[n + 1]);
  const char* hp = (const char*)h3p;
  float a0 = 0.f, a1 = 0.f, a2 = 0.f, ss = 0.f;
  for (int i = row + lane; i < end; i += 64) {
    int s = csr_src[i];
    float4 hv = *(const float4*)(hp + ((unsigned)s * 16u));
    float e = hv.w + aldv;
    e = fmaxf(e, 0.2f * e);
    float ex = __expf(e);
    ss += ex;
    a0 += ex * hv.x;
    a1 += ex * hv.y;
    a2 += ex * hv.z;
  }
#pragma unroll
  for (int off = 32; off >= 1; off >>= 1) {
    a0 += __shfl_xor(a0, off, 64);
    a1 += __shfl_xor(a1, off, 64);
    a2 += __shfl_xor(a2, off, 64);
    ss += __shfl_xor(ss, off, 64);
  }
  if (lane == 0) {
    float inv = 1.f / (ss + 1e-16f);
    float o0 = a0 * inv + b3[0];
    float o1 = a1 * inv + b3[1];
    float o2 = a2 * inv + b3[2];
    float m = fmaxf(o0, fmaxf(o1, o2));
    float lse = m + logf(expf(o0 - m) + expf(o1 - m) + expf(o2 - m));
    out[n * 3 + 0] = o0 - lse;
    out[n * 3 + 1] = o1 - lse;
    out[n * 3 + 2] = o2 - lse;
  }
}

// ---------------------------------------------------------------------------

extern "C" void kernel_launch(void* const* d_in, const int* in_sizes, int n_in,
                              void* d_out, int out_size, void* d_ws, size_t ws_size,
                              hipStream_t stream) {
  const float* x   = (const float*)d_in[0];
  const int*   ei  = (const int*)d_in[1];
  const float* W1  = (const float*)d_in[2];
  const float* a1s = (const float*)d_in[3];
  const float* a1d = (const float*)d_in[4];
  const float* b1  = (const float*)d_in[5];
  const float* g1v = (const float*)d_in[6];
  const float* be1 = (const float*)d_in[7];
  const float* m1  = (const float*)d_in[8];
  const float* v1  = (const float*)d_in[9];
  const float* W2  = (const float*)d_in[10];
  const float* a2s = (const float*)d_in[11];
  const float* a2d = (const float*)d_in[12];
  const float* b2  = (const float*)d_in[13];
  const float* g2v = (const float*)d_in[14];
  const float* be2 = (const float*)d_in[15];
  const float* m2  = (const float*)d_in[16];
  const float* v2  = (const float*)d_in[17];
  const float* W3  = (const float*)d_in[18];
  const float* a3s = (const float*)d_in[19];
  const float* a3d = (const float*)d_in[20];
  const float* b3  = (const float*)d_in[21];
  float* out = (float*)d_out;

  const int N = in_sizes[0] / 128;  // 50000
  const int E = in_sizes[1] / 2;    // 850000
  const int* srcv = ei;
  const int* dstv = ei + E;

  // workspace carve-up (~75 MB)
  float* wsf  = (float*)d_ws;
  float* als1 = wsf;                  // N*4
  float* ald1 = als1 + (size_t)N * 4;
  float* als2 = ald1 + (size_t)N * 4;
  float* ald2 = als2 + (size_t)N * 4;
  float* h3p  = ald2 + (size_t)N * 4;  // N*4 (float4 rows)
  float* ald3 = h3p + (size_t)N * 4;   // N
  unsigned short* h1s   = (unsigned short*)(ald3 + N);  // N*256 (8 subtables N*32)
  unsigned short* o1_bf = h1s + (size_t)N * 256;        // N*256 row-major phys
  unsigned short* h2s   = o1_bf + (size_t)N * 256;      // N*128 (8 subtables N*16)
  unsigned short* W1t   = h2s + (size_t)N * 128;        // 256*128
  unsigned short* W2t   = W1t + 256 * 128;              // 128*256
  int* deg       = (int*)(W2t + 128 * 256);  // N
  int* row_start = deg + N;                  // N+1
  int* cursor    = row_start + (N + 1);      // N+1
  int* csr_src   = cursor + (N + 1);         // E
  int* bsum      = csr_src + E;              // 1024
  // o2 (f32, N*128) reuses the retired h1s region (N*256 shorts = N*128 floats)
  float* o2f = (float*)h1s;

  const int eb = (E + 255) / 256;
  const int nb = (N + 1023) / 1024;
  const int nodes4 = (N + 3) / 4;
  const int mblocks = (N + 63) / 64;
  const int sliceblocks = ((N + 7) / 8) * 8;  // (node-groups) x 8 slices

  // weight conversions
  conv_w1t_kernel<<<128, 256, 0, stream>>>(W1, W1t);
  conv_w2t_kernel<<<128, 256, 0, stream>>>(W2, W2t);

  // CSR build (shared by all 3 layers)
  hipMemsetAsync(deg, 0, (size_t)N * sizeof(int), stream);
  hist_kernel<<<eb, 256, 0, stream>>>(dstv, E, deg);
  block_sums_kernel<<<nb, 256, 0, stream>>>(deg, N, bsum);
  tiny_scan_kernel<<<1, 64, 0, stream>>>(bsum, nb);
  scan_write_kernel<<<nb, 256, 0, stream>>>(deg, N, bsum, row_start, cursor);
  scatter_kernel<<<eb, 256, 0, stream>>>(srcv, dstv, E, cursor, csr_src);

  // layer 1: h1 = x @ W1 (f32 A converted in staging), fused als1/ald1
  gemm_mfma<128, 256, true><<<mblocks, 256, 0, stream>>>(x, W1t, a1s, a1d, h1s, als1,
                                                         ald1, N);
  gat_agg_slice<256><<<sliceblocks, 256, 0, stream>>>(
      h1s, als1, ald1, row_start, csr_src, b1, g1v, be1, m1, v1, o1_bf, nullptr, N);
  // layer 2
  gemm_mfma<256, 128, false><<<mblocks, 256, 0, stream>>>(o1_bf, W2t, a2s, a2d, h2s, als2,
                                                          ald2, N);
  gat_agg_slice<128><<<sliceblocks, 256, 0, stream>>>(
      h2s, als2, ald2, row_start, csr_src, b2, g2v, be2, m2, v2, nullptr, o2f, N);
  // layer 3 prep + aggregation + log_softmax
  l3_prep_kernel<<<nodes4, 256, 0, stream>>>(o2f, W3, a3s, a3d, (float4*)h3p, ald3, N);
  l3_agg_kernel<<<nodes4, 256, 0, stream>>>((const float4*)h3p, ald3, row_start, csr_src,
                                            b3, out, N);
}

// Round 5
// 557.665 us; speedup vs baseline: 1.1783x; 1.1783x over previous
//
#include <hip/hip_runtime.h>

// ---------------------------------------------------------------------------
// DoshaGAT: 3-layer GAT. R9 (= R8 + compile fix: ext-vector uint2v for
// nontemporal store; HIP_vector_type uint2 is rejected by the builtin):
//  - Keep R7's XCD slicing (FETCH 252->65MB confirmed) but strip its 8x
//    per-edge redundancy: alpha_kernel precomputes NORMALIZED softmax
//    coefficients alpha[4][E] (CSR-ordered planes) once per layer; the
//    sliced aggregate is a pure gather-FMA: s=csr[i], a=alpha[i], u=h[s],
//    acc+=a*u. No exp/ssum/als in the sliced loop.
//  - nt loads removed (R7's nt csr = no-allocate HBM-latency serial chain);
//    nt kept on output stores only.
//  - 8 edge-slots x 8 feat-lanes per wave (uint2 for D=256, uint for D=128);
//    masked tail hoisted out of the main loop.
//  - ws re-laid: alpha1 aliases h2s (written later), alpha2 aliases o1_bf
//    (dead after gemm2). Total ~73 MB.
// ---------------------------------------------------------------------------

#define WSZ 64

typedef short short8 __attribute__((ext_vector_type(8)));
typedef short short4v __attribute__((ext_vector_type(4)));
typedef float float4v __attribute__((ext_vector_type(4)));
typedef float f2v __attribute__((ext_vector_type(2)));
typedef unsigned uint2v __attribute__((ext_vector_type(2)));

__device__ inline unsigned short f2bf(float f) {  // RNE f32->bf16
  unsigned u = __float_as_uint(f);
  u += 0x7FFFu + ((u >> 16) & 1u);
  return (unsigned short)(u >> 16);
}
__device__ inline float bf2f(unsigned short u) {
  return __uint_as_float(((unsigned)u) << 16);
}

// ---------------- CSR build ----------------

__global__ __launch_bounds__(256) void hist_kernel(const int* __restrict__ dst, int E,
                                                   int* __restrict__ deg) {
  int e = blockIdx.x * 256 + threadIdx.x;
  if (e < E) atomicAdd(&deg[dst[e]], 1);
}

__global__ __launch_bounds__(256) void block_sums_kernel(const int* __restrict__ deg, int n,
                                                         int* __restrict__ bsum) {
  __shared__ int sh[256];
  int t = threadIdx.x;
  int base = blockIdx.x * 1024 + t * 4;
  int v = 0;
#pragma unroll
  for (int j = 0; j < 4; ++j) {
    int idx = base + j;
    if (idx < n) v += deg[idx];
  }
  sh[t] = v;
  __syncthreads();
  for (int off = 128; off >= 1; off >>= 1) {
    if (t < off) sh[t] += sh[t + off];
    __syncthreads();
  }
  if (t == 0) bsum[blockIdx.x] = sh[0];
}

__global__ void tiny_scan_kernel(int* bsum, int nb) {
  if (threadIdx.x == 0 && blockIdx.x == 0) {
    int run = 0;
    for (int i = 0; i < nb; ++i) {
      int v = bsum[i];
      bsum[i] = run;
      run += v;
    }
  }
}

__global__ __launch_bounds__(256) void scan_write_kernel(const int* __restrict__ deg, int n,
                                                         const int* __restrict__ bbase,
                                                         int* __restrict__ row_start,
                                                         int* __restrict__ cursor) {
  __shared__ int sh[256];
  int t = threadIdx.x;
  int base = blockIdx.x * 1024 + t * 4;
  int v[4];
  int s = 0;
#pragma unroll
  for (int j = 0; j < 4; ++j) {
    int idx = base + j;
    v[j] = (idx < n) ? deg[idx] : 0;
    s += v[j];
  }
  sh[t] = s;
  __syncthreads();
  for (int off = 1; off < 256; off <<= 1) {
    int x = (t >= off) ? sh[t - off] : 0;
    __syncthreads();
    sh[t] += x;
    __syncthreads();
  }
  int excl = sh[t] - s + bbase[blockIdx.x];
#pragma unroll
  for (int j = 0; j < 4; ++j) {
    int idx = base + j;
    if (idx < n) {
      row_start[idx] = excl;
      cursor[idx] = excl;
    }
    excl += v[j];
  }
  if (blockIdx.x == gridDim.x - 1 && t == 255) row_start[n] = excl;  // == E
}

__global__ __launch_bounds__(256) void scatter_kernel(const int* __restrict__ src,
                                                      const int* __restrict__ dst, int E,
                                                      int* __restrict__ cursor,
                                                      int* __restrict__ csr_src) {
  int e = blockIdx.x * 256 + threadIdx.x;
  if (e < E) {
    int d = dst[e];
    int p = atomicAdd(&cursor[d], 1);
    csr_src[p] = src[e];
  }
}

// ---------------- weight conversion ----------------

// W1 [128][256] -> W1t [256][128] bf16
__global__ __launch_bounds__(256) void conv_w1t_kernel(const float* __restrict__ W1,
                                                       unsigned short* __restrict__ W1t) {
  int idx = blockIdx.x * 256 + threadIdx.x;  // 32768
  int n = idx >> 7, k = idx & 127;
  W1t[idx] = f2bf(W1[k * 256 + n]);
}

// W2 [256][128] -> W2t [128][256] bf16, K rows permuted to layer-1 phys layout
__global__ __launch_bounds__(256) void conv_w2t_kernel(const float* __restrict__ W2,
                                                       unsigned short* __restrict__ W2t) {
  int idx = blockIdx.x * 256 + threadIdx.x;  // 32768
  int n = idx >> 8, p = idx & 255;
  int kl = (p & ~63) | ((p & 3) << 4) | ((p >> 2) & 15);
  W2t[idx] = f2bf(W2[kl * 128 + n]);
}

// ---------------- bf16 MFMA GEMM + fused attn-coeff epilogue ----------------
// C[M,BN] = A[M,K] @ B[K,BN]. 64-row blocks, 256 threads, 4 waves (wave=head).
// AF32: A is f32, converted to bf16 during LDS staging.
// hout is written SLICE-MAJOR: 8 subtables of [M][BN/8] bf16.

template <int K, int BN, bool AF32>
__global__ __launch_bounds__(256) void gemm_mfma(
    const void* __restrict__ Ap,            // [M][K] bf16 or f32
    const unsigned short* __restrict__ Bt,  // [BN][K] bf16 (pre-transposed)
    const float* __restrict__ a_s, const float* __restrict__ a_d,  // [BN] logical
    unsigned short* __restrict__ hout,      // slice-major output
    float* __restrict__ als, float* __restrict__ ald,  // [M][4]
    int M) {
  constexpr int CF = BN / 64;  // col frags per wave
  constexpr int SF = BN / 8;   // feats per slice (32 or 16)
  constexpr int PAD = 36;
  __shared__ unsigned short As[64][PAD];
  __shared__ unsigned short Bs[BN][PAD];
  const int t = threadIdx.x;
  const int w = t >> 6;
  const int lane = t & 63;
  const int c16 = lane & 15;
  const int q = lane >> 4;
  const int bm = blockIdx.x * 64;
  const int arow = t >> 2;      // 0..63
  const int akc = (t & 3) * 8;  // 0,8,16,24

  float4v acc[4][CF];
#pragma unroll
  for (int rf = 0; rf < 4; ++rf)
#pragma unroll
    for (int cf = 0; cf < CF; ++cf) acc[rf][cf] = float4v{0.f, 0.f, 0.f, 0.f};

  for (int k0 = 0; k0 < K; k0 += 32) {
    {  // stage A tile 64x32 (8 elems/thread)
      int gr = bm + arow;
      if constexpr (AF32) {
        const float* Af = (const float*)Ap + (size_t)gr * K + k0 + akc;
        float4 v0 = make_float4(0.f, 0.f, 0.f, 0.f), v1 = v0;
        if (gr < M) {
          v0 = *(const float4*)Af;
          v1 = *(const float4*)(Af + 4);
        }
        ushort4 u0, u1;
        u0.x = f2bf(v0.x); u0.y = f2bf(v0.y); u0.z = f2bf(v0.z); u0.w = f2bf(v0.w);
        u1.x = f2bf(v1.x); u1.y = f2bf(v1.y); u1.z = f2bf(v1.z); u1.w = f2bf(v1.w);
        *(ushort4*)&As[arow][akc] = u0;
        *(ushort4*)&As[arow][akc + 4] = u1;
      } else {
        uint4 v = make_uint4(0u, 0u, 0u, 0u);
        if (gr < M) v = *(const uint4*)((const unsigned short*)Ap + (size_t)gr * K + k0 + akc);
        *(uint2*)&As[arow][akc] = make_uint2(v.x, v.y);
        *(uint2*)&As[arow][akc + 4] = make_uint2(v.z, v.w);
      }
    }
#pragma unroll
    for (int h = 0; h < BN / 64; ++h) {  // stage B tile BNx32
      int n = (t >> 2) + h * 64;
      uint4 v = *(const uint4*)(Bt + (size_t)n * K + k0 + akc);
      *(uint2*)&Bs[n][akc] = make_uint2(v.x, v.y);
      *(uint2*)&Bs[n][akc + 4] = make_uint2(v.z, v.w);
    }
    __syncthreads();
    short8 af[4], bfr[CF];
#pragma unroll
    for (int rf = 0; rf < 4; ++rf) {
      short4v lo = *(short4v*)&As[rf * 16 + c16][q * 8];
      short4v hi = *(short4v*)&As[rf * 16 + c16][q * 8 + 4];
      af[rf] = __builtin_shufflevector(lo, hi, 0, 1, 2, 3, 4, 5, 6, 7);
    }
#pragma unroll
    for (int cf = 0; cf < CF; ++cf) {
      int n = w * (CF * 16) + cf * 16 + c16;
      short4v lo = *(short4v*)&Bs[n][q * 8];
      short4v hi = *(short4v*)&Bs[n][q * 8 + 4];
      bfr[cf] = __builtin_shufflevector(lo, hi, 0, 1, 2, 3, 4, 5, 6, 7);
    }
#pragma unroll
    for (int rf = 0; rf < 4; ++rf)
#pragma unroll
      for (int cf = 0; cf < CF; ++cf)
        acc[rf][cf] =
            __builtin_amdgcn_mfma_f32_16x16x32_bf16(af[rf], bfr[cf], acc[rf][cf], 0, 0, 0);
    __syncthreads();
  }

  float sasv[CF], sadv[CF];
#pragma unroll
  for (int cf = 0; cf < CF; ++cf) {
    int L = w * (CF * 16) + cf * 16 + c16;
    sasv[cf] = a_s[L];
    sadv[cf] = a_d[L];
  }
  // slice-major store base: subtable = w*2 + (c16>>3)
  const size_t sub = (size_t)(w * 2 + (c16 >> 3)) * (size_t)M * SF;
#pragma unroll
  for (int rf = 0; rf < 4; ++rf) {
#pragma unroll
    for (int r = 0; r < 4; ++r) {
      int n = bm + rf * 16 + q * 4 + r;
      float ps = 0.f, pd = 0.f;
      unsigned short us[CF];
#pragma unroll
      for (int cf = 0; cf < CF; ++cf) {
        float v = acc[rf][cf][r];
        us[cf] = f2bf(v);
        ps += v * sasv[cf];
        pd += v * sadv[cf];
      }
#pragma unroll
      for (int off = 1; off <= 8; off <<= 1) {
        ps += __shfl_xor(ps, off, 16);
        pd += __shfl_xor(pd, off, 16);
      }
      if (n < M) {
        if constexpr (CF == 4) {
          ushort4 u;
          u.x = us[0]; u.y = us[1]; u.z = us[2]; u.w = us[3];
          *(ushort4*)(hout + sub + (size_t)n * 32 + (c16 & 7) * 4) = u;
        } else {
          ushort2 u;
          u.x = us[0]; u.y = us[1];
          *(ushort2*)(hout + sub + (size_t)n * 16 + (c16 & 7) * 2) = u;
        }
        if (c16 == 0) {
          als[(size_t)n * 4 + w] = ps;
          ald[(size_t)n * 4 + w] = pd;
        }
      }
    }
  }
}

// ---------------- alpha precompute: normalized softmax coefficients --------
// Wave per node; lanes = 16 edge-slots x 4 heads. Pass A: ssum per head.
// Pass B: alpha[head][e] = exp(leaky(als[s]+ald[n]))*inv. CSR-ordered planes.

__global__ __launch_bounds__(256) void alpha_kernel(
    const float* __restrict__ als, const float* __restrict__ ald,
    const int* __restrict__ row_start, const int* __restrict__ csr_src,
    float* __restrict__ alpha, int E, int n_nodes) {
  int wid = threadIdx.x >> 6, lane = threadIdx.x & 63;
  int n = __builtin_amdgcn_readfirstlane(blockIdx.x * 4 + wid);
  if (n >= n_nodes) return;
  int head = lane & 3;
  int eg = lane >> 2;  // 16 edge slots
  float aldv = ald[(size_t)n * 4 + head];
  int row = __builtin_amdgcn_readfirstlane(row_start[n]);
  int end = __builtin_amdgcn_readfirstlane(row_start[n + 1]);
  float ssum = 0.f;
  for (int i = row; i < end; i += 16) {
    int e = i + eg;
    int ec = (e < end) ? e : (end - 1);
    int s = csr_src[ec];
    float x = als[(size_t)(unsigned)s * 4 + head] + aldv;
    x = fmaxf(x, 0.2f * x);
    float ex = __expf(x);
    ssum += (e < end) ? ex : 0.f;
  }
  ssum += __shfl_xor(ssum, 4, 64);
  ssum += __shfl_xor(ssum, 8, 64);
  ssum += __shfl_xor(ssum, 16, 64);
  ssum += __shfl_xor(ssum, 32, 64);
  float inv = 1.f / (ssum + 1e-16f);
  float* apl = alpha + (size_t)head * (unsigned)E;
  for (int i = row; i < end; i += 16) {
    int e = i + eg;
    if (e < end) {
      int s = csr_src[e];
      float x = als[(size_t)(unsigned)s * 4 + head] + aldv;
      x = fmaxf(x, 0.2f * x);
      apl[e] = __expf(x) * inv;
    }
  }
}

// ---------------- XCD-sliced GAT aggregation + bias + BN + ELU --------------
// slice = blockIdx%8 -> XCD affinity; per-XCD h working set 3.2MB/1.6MB (L2).
// Wave per (node, slice): 8 edge-slots x 8 feat-lanes. Pure gather-FMA loop
// (alpha pre-normalized). Plain cached loads; nt stores only.

template <int D>
__global__ __launch_bounds__(256) void gat_agg_slice(
    const unsigned short* __restrict__ h_sl,  // 8 slice-major subtables
    const float* __restrict__ alpha,          // [4][E]
    const int* __restrict__ row_start, const int* __restrict__ csr_src,
    const float* __restrict__ bias, const float* __restrict__ gamma,
    const float* __restrict__ beta, const float* __restrict__ bmean,
    const float* __restrict__ bvar,
    unsigned short* __restrict__ obf,  // D==256 out (bf16 phys rows)
    float* __restrict__ of32,          // D==128 out (f32 phys rows)
    int E, int n_nodes) {
  constexpr int SFEAT = D / 8;  // 32 | 16
  const int sl = blockIdx.x & 7;
  const int g = blockIdx.x >> 3;
  const int wid = threadIdx.x >> 6, lane = threadIdx.x & 63;
  const int f = lane & 7;   // feat slot
  const int eg = lane >> 3; // edge slot 0..7
  const int head = sl >> 1;
  const char* hb = (const char*)(h_sl + (size_t)sl * (unsigned)n_nodes * SFEAT);
  const char* cb = (const char*)csr_src;
  const char* apb = (const char*)(alpha + (size_t)head * (unsigned)E);
  const unsigned uoff = (unsigned)(f * (SFEAT / 8) * 2);  // byte off in slice row

  int n = __builtin_amdgcn_readfirstlane(g * 4 + wid);
  if (n >= n_nodes) return;
  int row = __builtin_amdgcn_readfirstlane(row_start[n]);
  int end = __builtin_amdgcn_readfirstlane(row_start[n + 1]);
  float acc0 = 0.f, acc1 = 0.f, acc2 = 0.f, acc3 = 0.f;

  int i = row;
#pragma unroll 2
  for (; i + 8 <= end; i += 8) {
    unsigned idx = (unsigned)(i + eg);
    int s = *(const int*)(cb + idx * 4u);
    float a = *(const float*)(apb + idx * 4u);
    if constexpr (D == 256) {
      uint2v u = *(const uint2v*)(hb + ((unsigned)s * 64u + uoff));
      acc0 += a * __uint_as_float(u.x << 16);
      acc1 += a * __uint_as_float(u.x & 0xffff0000u);
      acc2 += a * __uint_as_float(u.y << 16);
      acc3 += a * __uint_as_float(u.y & 0xffff0000u);
    } else {
      unsigned u = *(const unsigned*)(hb + ((unsigned)s * 32u + uoff));
      acc0 += a * __uint_as_float(u << 16);
      acc1 += a * __uint_as_float(u & 0xffff0000u);
    }
  }
  if (i < end) {  // masked last block
    int e = i + eg;
    unsigned idx = (unsigned)((e < end) ? e : (end - 1));
    int s = *(const int*)(cb + idx * 4u);
    float a = (e < end) ? *(const float*)(apb + idx * 4u) : 0.f;
    if constexpr (D == 256) {
      uint2v u = *(const uint2v*)(hb + ((unsigned)s * 64u + uoff));
      acc0 += a * __uint_as_float(u.x << 16);
      acc1 += a * __uint_as_float(u.x & 0xffff0000u);
      acc2 += a * __uint_as_float(u.y << 16);
      acc3 += a * __uint_as_float(u.y & 0xffff0000u);
    } else {
      unsigned u = *(const unsigned*)(hb + ((unsigned)s * 32u + uoff));
      acc0 += a * __uint_as_float(u << 16);
      acc1 += a * __uint_as_float(u & 0xffff0000u);
    }
  }

  // reduce over edge-slot dim (stride 8)
#pragma unroll
  for (int off = 8; off <= 32; off <<= 1) {
    acc0 += __shfl_xor(acc0, off, 64);
    acc1 += __shfl_xor(acc1, off, 64);
    if constexpr (D == 256) {
      acc2 += __shfl_xor(acc2, off, 64);
      acc3 += __shfl_xor(acc3, off, 64);
    }
  }

  if (eg == 0) {
    if constexpr (D == 256) {
      // logical col of acc[k]: head*64 + k*16 + (sl&1)*8 + f
      float o[4] = {acc0, acc1, acc2, acc3};
      unsigned short us[4];
#pragma unroll
      for (int k = 0; k < 4; ++k) {
        int l = head * 64 + k * 16 + (sl & 1) * 8 + f;
        float v = o[k] + bias[l];
        v = (v - bmean[l]) * rsqrtf(bvar[l] + 1e-5f) * gamma[l] + beta[l];
        v = (v > 0.f) ? v : (__expf(v) - 1.f);
        us[k] = f2bf(v);
      }
      uint2v pk;
      pk.x = (unsigned)us[0] | ((unsigned)us[1] << 16);
      pk.y = (unsigned)us[2] | ((unsigned)us[3] << 16);
      __builtin_nontemporal_store(
          pk, (uint2v*)(obf + (size_t)n * 256 + sl * 32 + f * 4));
    } else {
      // logical col of acc[j]: head*32 + j*16 + (sl&1)*8 + f
      float o[2] = {acc0, acc1};
      f2v v2;
#pragma unroll
      for (int j = 0; j < 2; ++j) {
        int l = head * 32 + j * 16 + (sl & 1) * 8 + f;
        float v = o[j] + bias[l];
        v = (v - bmean[l]) * rsqrtf(bvar[l] + 1e-5f) * gamma[l] + beta[l];
        v = (v > 0.f) ? v : (__expf(v) - 1.f);
        v2[j] = v;
      }
      __builtin_nontemporal_store(
          v2, (f2v*)(of32 + (size_t)n * 128 + sl * 16 + f * 2));
    }
  }
}

// ---------------- layer-3 prep: h3 = o2 @ W3, als3/ald3 ---------------------

__global__ __launch_bounds__(256) void l3_prep_kernel(
    const float* __restrict__ o2, const float* __restrict__ W3,
    const float* __restrict__ a3s, const float* __restrict__ a3d,
    float4* __restrict__ h3p, float* __restrict__ ald3, int n_nodes) {
  __shared__ float w3s[384];
  __shared__ float sa3[6];
  for (int i = threadIdx.x; i < 384; i += 256) w3s[i] = W3[i];
  if (threadIdx.x < 3) {
    sa3[threadIdx.x] = a3s[threadIdx.x];
    sa3[3 + threadIdx.x] = a3d[threadIdx.x];
  }
  __syncthreads();
  int wid = threadIdx.x >> 6, lane = threadIdx.x & 63;
  int n = blockIdx.x * 4 + wid;
  if (n >= n_nodes) return;
  f2v v = *(const f2v*)(o2 + (size_t)n * 128 + lane * 2);  // phys cols lane*2,+1
  int hd = lane >> 4;
  int k0l = hd * 32 + (lane & 15);  // logical k of phys col lane*2
  int k1l = k0l + 16;               // logical k of phys col lane*2+1
  float p0 = v.x * w3s[k0l * 3 + 0] + v.y * w3s[k1l * 3 + 0];
  float p1 = v.x * w3s[k0l * 3 + 1] + v.y * w3s[k1l * 3 + 1];
  float p2 = v.x * w3s[k0l * 3 + 2] + v.y * w3s[k1l * 3 + 2];
#pragma unroll
  for (int off = 32; off >= 1; off >>= 1) {
    p0 += __shfl_xor(p0, off, 64);
    p1 += __shfl_xor(p1, off, 64);
    p2 += __shfl_xor(p2, off, 64);
  }
  if (lane == 0) {
    float als3 = p0 * sa3[0] + p1 * sa3[1] + p2 * sa3[2];
    float ad3 = p0 * sa3[3] + p1 * sa3[4] + p2 * sa3[5];
    h3p[n] = make_float4(p0, p1, p2, als3);
    ald3[n] = ad3;
  }
}

// ---------------- layer 3 aggregation + log_softmax -------------------------

__global__ __launch_bounds__(256) void l3_agg_kernel(const float4* __restrict__ h3p,
                                                     const float* __restrict__ ald3,
                                                     const int* __restrict__ row_start,
                                                     const int* __restrict__ csr_src,
                                                     const float* __restrict__ b3,
                                                     float* __restrict__ out, int n_nodes) {
  int wid = threadIdx.x >> 6, lane = threadIdx.x & 63;
  int n = __builtin_amdgcn_readfirstlane(blockIdx.x * 4 + wid);
  if (n >= n_nodes) return;
  float aldv = ald3[n];
  int row = __builtin_amdgcn_readfirstlane(row_start[n]);
  int end = __builtin_amdgcn_readfirstlane(row_start[n + 1]);
  const char* hp = (const char*)h3p;
  float a0 = 0.f, a1 = 0.f, a2 = 0.f, ss = 0.f;
  for (int i = row + lane; i < end; i += 64) {
    int s = csr_src[i];
    float4 hv = *(const float4*)(hp + ((unsigned)s * 16u));
    float e = hv.w + aldv;
    e = fmaxf(e, 0.2f * e);
    float ex = __expf(e);
    ss += ex;
    a0 += ex * hv.x;
    a1 += ex * hv.y;
    a2 += ex * hv.z;
  }
#pragma unroll
  for (int off = 32; off >= 1; off >>= 1) {
    a0 += __shfl_xor(a0, off, 64);
    a1 += __shfl_xor(a1, off, 64);
    a2 += __shfl_xor(a2, off, 64);
    ss += __shfl_xor(ss, off, 64);
  }
  if (lane == 0) {
    float inv = 1.f / (ss + 1e-16f);
    float o0 = a0 * inv + b3[0];
    float o1 = a1 * inv + b3[1];
    float o2 = a2 * inv + b3[2];
    float m = fmaxf(o0, fmaxf(o1, o2));
    float lse = m + logf(expf(o0 - m) + expf(o1 - m) + expf(o2 - m));
    out[n * 3 + 0] = o0 - lse;
    out[n * 3 + 1] = o1 - lse;
    out[n * 3 + 2] = o2 - lse;
  }
}

// ---------------------------------------------------------------------------

extern "C" void kernel_launch(void* const* d_in, const int* in_sizes, int n_in,
                              void* d_out, int out_size, void* d_ws, size_t ws_size,
                              hipStream_t stream) {
  const float* x   = (const float*)d_in[0];
  const int*   ei  = (const int*)d_in[1];
  const float* W1  = (const float*)d_in[2];
  const float* a1s = (const float*)d_in[3];
  const float* a1d = (const float*)d_in[4];
  const float* b1  = (const float*)d_in[5];
  const float* g1v = (const float*)d_in[6];
  const float* be1 = (const float*)d_in[7];
  const float* m1  = (const float*)d_in[8];
  const float* v1  = (const float*)d_in[9];
  const float* W2  = (const float*)d_in[10];
  const float* a2s = (const float*)d_in[11];
  const float* a2d = (const float*)d_in[12];
  const float* b2  = (const float*)d_in[13];
  const float* g2v = (const float*)d_in[14];
  const float* be2 = (const float*)d_in[15];
  const float* m2  = (const float*)d_in[16];
  const float* v2  = (const float*)d_in[17];
  const float* W3  = (const float*)d_in[18];
  const float* a3s = (const float*)d_in[19];
  const float* a3d = (const float*)d_in[20];
  const float* b3  = (const float*)d_in[21];
  float* out = (float*)d_out;

  const int N = in_sizes[0] / 128;  // 50000
  const int E = in_sizes[1] / 2;    // 850000
  const int* srcv = ei;
  const int* dstv = ei + E;

  // workspace carve-up (~73 MB), h2s LAST so alpha1 can alias + spill past it
  float* wsf  = (float*)d_ws;
  float* als1 = wsf;                   // N*4
  float* ald1 = als1 + (size_t)N * 4;
  float* als2 = ald1 + (size_t)N * 4;
  float* ald2 = als2 + (size_t)N * 4;
  float* h3p  = ald2 + (size_t)N * 4;  // N*4 (float4 rows)
  float* ald3 = h3p + (size_t)N * 4;   // N
  unsigned short* h1s   = (unsigned short*)(ald3 + N);  // N*256 (8 subtables N*32)
  unsigned short* o1_bf = h1s + (size_t)N * 256;        // N*256 row-major phys
  unsigned short* W1t   = o1_bf + (size_t)N * 256;      // 256*128
  unsigned short* W2t   = W1t + 256 * 128;              // 128*256
  int* deg       = (int*)(W2t + 128 * 256);  // N
  int* row_start = deg + N;                  // N+1
  int* cursor    = row_start + (N + 1);      // N+1
  int* csr_src   = cursor + (N + 1);         // E
  int* bsum      = csr_src + E;              // 1024
  unsigned short* h2s = (unsigned short*)(bsum + 1024);  // N*128 (8 subtables N*16) LAST
  // aliases (lifetimes disjoint):
  float* alpha1 = (float*)h2s;    // 4*E f32; dead before gemm2 writes h2s
  float* alpha2 = (float*)o1_bf;  // 4*E f32; o1_bf dead after gemm2 reads it
  float* o2f    = (float*)h1s;    // N*128 f32; h1s dead after agg1

  const int eb = (E + 255) / 256;
  const int nb = (N + 1023) / 1024;
  const int nodes4 = (N + 3) / 4;
  const int mblocks = (N + 63) / 64;
  const int sliceblocks = nodes4 * 8;  // (node-groups) x 8 slices

  // weight conversions
  conv_w1t_kernel<<<128, 256, 0, stream>>>(W1, W1t);
  conv_w2t_kernel<<<128, 256, 0, stream>>>(W2, W2t);

  // CSR build (shared by all 3 layers)
  hipMemsetAsync(deg, 0, (size_t)N * sizeof(int), stream);
  hist_kernel<<<eb, 256, 0, stream>>>(dstv, E, deg);
  block_sums_kernel<<<nb, 256, 0, stream>>>(deg, N, bsum);
  tiny_scan_kernel<<<1, 64, 0, stream>>>(bsum, nb);
  scan_write_kernel<<<nb, 256, 0, stream>>>(deg, N, bsum, row_start, cursor);
  scatter_kernel<<<eb, 256, 0, stream>>>(srcv, dstv, E, cursor, csr_src);

  // layer 1
  gemm_mfma<128, 256, true><<<mblocks, 256, 0, stream>>>(x, W1t, a1s, a1d, h1s, als1,
                                                         ald1, N);
  alpha_kernel<<<nodes4, 256, 0, stream>>>(als1, ald1, row_start, csr_src, alpha1, E, N);
  gat_agg_slice<256><<<sliceblocks, 256, 0, stream>>>(
      h1s, alpha1, row_start, csr_src, b1, g1v, be1, m1, v1, o1_bf, nullptr, E, N);
  // layer 2
  gemm_mfma<256, 128, false><<<mblocks, 256, 0, stream>>>(o1_bf, W2t, a2s, a2d, h2s, als2,
                                                          ald2, N);
  alpha_kernel<<<nodes4, 256, 0, stream>>>(als2, ald2, row_start, csr_src, alpha2, E, N);
  gat_agg_slice<128><<<sliceblocks, 256, 0, stream>>>(
      h2s, alpha2, row_start, csr_src, b2, g2v, be2, m2, v2, nullptr, o2f, E, N);
  // layer 3 prep + aggregation + log_softmax
  l3_prep_kernel<<<nodes4, 256, 0, stream>>>(o2f, W3, a3s, a3d, (float4*)h3p, ald3, N);
  l3_agg_kernel<<<nodes4, 256, 0, stream>>>((const float4*)h3p, ald3, row_start, csr_src,
                                            b3, out, N);
}

// Round 6
// 455.902 us; speedup vs baseline: 1.4413x; 1.2232x over previous
//
#include <hip/hip_runtime.h>

// ---------------------------------------------------------------------------
// DoshaGAT: 3-layer GAT. R10:
//  - Sliced aggregates restructured: 8 nodes x 8 feat-lanes per wave; each
//    8-lane group serially walks one node's edges (no cross-lane reduction;
//    uniform wave-max-degree loop with masked/clamped inactive lanes).
//    Kills R9's per-(node,slice) fixed cost (was 400k waves x ~150 instr).
//  - bn_prep precomputes BN scale/shift per logical col; agg epilogue is
//    fma+ELU+pack+nt-store (was 20 loads + rsqrt per node-slice).
//  - Everything else (slice-major h layout, alpha planes, XCD %8 affinity,
//    GEMM, l3) carried over verbatim from the passing R9.
// ---------------------------------------------------------------------------

#define WSZ 64

typedef short short8 __attribute__((ext_vector_type(8)));
typedef short short4v __attribute__((ext_vector_type(4)));
typedef float float4v __attribute__((ext_vector_type(4)));
typedef float f2v __attribute__((ext_vector_type(2)));
typedef unsigned uint2v __attribute__((ext_vector_type(2)));

__device__ inline unsigned short f2bf(float f) {  // RNE f32->bf16
  unsigned u = __float_as_uint(f);
  u += 0x7FFFu + ((u >> 16) & 1u);
  return (unsigned short)(u >> 16);
}
__device__ inline float bf2f(unsigned short u) {
  return __uint_as_float(((unsigned)u) << 16);
}

// ---------------- CSR build ----------------

__global__ __launch_bounds__(256) void hist_kernel(const int* __restrict__ dst, int E,
                                                   int* __restrict__ deg) {
  int e = blockIdx.x * 256 + threadIdx.x;
  if (e < E) atomicAdd(&deg[dst[e]], 1);
}

__global__ __launch_bounds__(256) void block_sums_kernel(const int* __restrict__ deg, int n,
                                                         int* __restrict__ bsum) {
  __shared__ int sh[256];
  int t = threadIdx.x;
  int base = blockIdx.x * 1024 + t * 4;
  int v = 0;
#pragma unroll
  for (int j = 0; j < 4; ++j) {
    int idx = base + j;
    if (idx < n) v += deg[idx];
  }
  sh[t] = v;
  __syncthreads();
  for (int off = 128; off >= 1; off >>= 1) {
    if (t < off) sh[t] += sh[t + off];
    __syncthreads();
  }
  if (t == 0) bsum[blockIdx.x] = sh[0];
}

__global__ void tiny_scan_kernel(int* bsum, int nb) {
  if (threadIdx.x == 0 && blockIdx.x == 0) {
    int run = 0;
    for (int i = 0; i < nb; ++i) {
      int v = bsum[i];
      bsum[i] = run;
      run += v;
    }
  }
}

__global__ __launch_bounds__(256) void scan_write_kernel(const int* __restrict__ deg, int n,
                                                         const int* __restrict__ bbase,
                                                         int* __restrict__ row_start,
                                                         int* __restrict__ cursor) {
  __shared__ int sh[256];
  int t = threadIdx.x;
  int base = blockIdx.x * 1024 + t * 4;
  int v[4];
  int s = 0;
#pragma unroll
  for (int j = 0; j < 4; ++j) {
    int idx = base + j;
    v[j] = (idx < n) ? deg[idx] : 0;
    s += v[j];
  }
  sh[t] = s;
  __syncthreads();
  for (int off = 1; off < 256; off <<= 1) {
    int x = (t >= off) ? sh[t - off] : 0;
    __syncthreads();
    sh[t] += x;
    __syncthreads();
  }
  int excl = sh[t] - s + bbase[blockIdx.x];
#pragma unroll
  for (int j = 0; j < 4; ++j) {
    int idx = base + j;
    if (idx < n) {
      row_start[idx] = excl;
      cursor[idx] = excl;
    }
    excl += v[j];
  }
  if (blockIdx.x == gridDim.x - 1 && t == 255) row_start[n] = excl;  // == E
}

__global__ __launch_bounds__(256) void scatter_kernel(const int* __restrict__ src,
                                                      const int* __restrict__ dst, int E,
                                                      int* __restrict__ cursor,
                                                      int* __restrict__ csr_src) {
  int e = blockIdx.x * 256 + threadIdx.x;
  if (e < E) {
    int d = dst[e];
    int p = atomicAdd(&cursor[d], 1);
    csr_src[p] = src[e];
  }
}

// ---------------- weight conversion + BN fold ----------------

// W1 [128][256] -> W1t [256][128] bf16
__global__ __launch_bounds__(256) void conv_w1t_kernel(const float* __restrict__ W1,
                                                       unsigned short* __restrict__ W1t) {
  int idx = blockIdx.x * 256 + threadIdx.x;  // 32768
  int n = idx >> 7, k = idx & 127;
  W1t[idx] = f2bf(W1[k * 256 + n]);
}

// W2 [256][128] -> W2t [128][256] bf16, K rows permuted to layer-1 phys layout
__global__ __launch_bounds__(256) void conv_w2t_kernel(const float* __restrict__ W2,
                                                       unsigned short* __restrict__ W2t) {
  int idx = blockIdx.x * 256 + threadIdx.x;  // 32768
  int n = idx >> 8, p = idx & 255;
  int kl = (p & ~63) | ((p & 3) << 4) | ((p >> 2) & 15);
  W2t[idx] = f2bf(W2[kl * 128 + n]);
}

// fold bias+BN into per-logical-col scale/shift: o*sc + sh
__global__ __launch_bounds__(512) void bn_prep_kernel(
    const float* __restrict__ b1, const float* __restrict__ g1,
    const float* __restrict__ be1, const float* __restrict__ m1,
    const float* __restrict__ v1, const float* __restrict__ b2,
    const float* __restrict__ g2, const float* __restrict__ be2,
    const float* __restrict__ m2, const float* __restrict__ v2,
    float* __restrict__ sc1, float* __restrict__ sh1,
    float* __restrict__ sc2, float* __restrict__ sh2) {
  int t = threadIdx.x;
  if (t < 256) {
    float s = g1[t] * rsqrtf(v1[t] + 1e-5f);
    sc1[t] = s;
    sh1[t] = (b1[t] - m1[t]) * s + be1[t];
  } else if (t < 384) {
    int i = t - 256;
    float s = g2[i] * rsqrtf(v2[i] + 1e-5f);
    sc2[i] = s;
    sh2[i] = (b2[i] - m2[i]) * s + be2[i];
  }
}

// ---------------- bf16 MFMA GEMM + fused attn-coeff epilogue ----------------
// C[M,BN] = A[M,K] @ B[K,BN]. 64-row blocks, 256 threads, 4 waves (wave=head).
// AF32: A is f32, converted to bf16 during LDS staging.
// hout is written SLICE-MAJOR: 8 subtables of [M][BN/8] bf16.

template <int K, int BN, bool AF32>
__global__ __launch_bounds__(256) void gemm_mfma(
    const void* __restrict__ Ap,            // [M][K] bf16 or f32
    const unsigned short* __restrict__ Bt,  // [BN][K] bf16 (pre-transposed)
    const float* __restrict__ a_s, const float* __restrict__ a_d,  // [BN] logical
    unsigned short* __restrict__ hout,      // slice-major output
    float* __restrict__ als, float* __restrict__ ald,  // [M][4]
    int M) {
  constexpr int CF = BN / 64;  // col frags per wave
  constexpr int SF = BN / 8;   // feats per slice (32 or 16)
  constexpr int PAD = 36;
  __shared__ unsigned short As[64][PAD];
  __shared__ unsigned short Bs[BN][PAD];
  const int t = threadIdx.x;
  const int w = t >> 6;
  const int lane = t & 63;
  const int c16 = lane & 15;
  const int q = lane >> 4;
  const int bm = blockIdx.x * 64;
  const int arow = t >> 2;      // 0..63
  const int akc = (t & 3) * 8;  // 0,8,16,24

  float4v acc[4][CF];
#pragma unroll
  for (int rf = 0; rf < 4; ++rf)
#pragma unroll
    for (int cf = 0; cf < CF; ++cf) acc[rf][cf] = float4v{0.f, 0.f, 0.f, 0.f};

  for (int k0 = 0; k0 < K; k0 += 32) {
    {  // stage A tile 64x32 (8 elems/thread)
      int gr = bm + arow;
      if constexpr (AF32) {
        const float* Af = (const float*)Ap + (size_t)gr * K + k0 + akc;
        float4 v0 = make_float4(0.f, 0.f, 0.f, 0.f), v1 = v0;
        if (gr < M) {
          v0 = *(const float4*)Af;
          v1 = *(const float4*)(Af + 4);
        }
        ushort4 u0, u1;
        u0.x = f2bf(v0.x); u0.y = f2bf(v0.y); u0.z = f2bf(v0.z); u0.w = f2bf(v0.w);
        u1.x = f2bf(v1.x); u1.y = f2bf(v1.y); u1.z = f2bf(v1.z); u1.w = f2bf(v1.w);
        *(ushort4*)&As[arow][akc] = u0;
        *(ushort4*)&As[arow][akc + 4] = u1;
      } else {
        uint4 v = make_uint4(0u, 0u, 0u, 0u);
        if (gr < M) v = *(const uint4*)((const unsigned short*)Ap + (size_t)gr * K + k0 + akc);
        *(uint2*)&As[arow][akc] = make_uint2(v.x, v.y);
        *(uint2*)&As[arow][akc + 4] = make_uint2(v.z, v.w);
      }
    }
#pragma unroll
    for (int h = 0; h < BN / 64; ++h) {  // stage B tile BNx32
      int n = (t >> 2) + h * 64;
      uint4 v = *(const uint4*)(Bt + (size_t)n * K + k0 + akc);
      *(uint2*)&Bs[n][akc] = make_uint2(v.x, v.y);
      *(uint2*)&Bs[n][akc + 4] = make_uint2(v.z, v.w);
    }
    __syncthreads();
    short8 af[4], bfr[CF];
#pragma unroll
    for (int rf = 0; rf < 4; ++rf) {
      short4v lo = *(short4v*)&As[rf * 16 + c16][q * 8];
      short4v hi = *(short4v*)&As[rf * 16 + c16][q * 8 + 4];
      af[rf] = __builtin_shufflevector(lo, hi, 0, 1, 2, 3, 4, 5, 6, 7);
    }
#pragma unroll
    for (int cf = 0; cf < CF; ++cf) {
      int n = w * (CF * 16) + cf * 16 + c16;
      short4v lo = *(short4v*)&Bs[n][q * 8];
      short4v hi = *(short4v*)&Bs[n][q * 8 + 4];
      bfr[cf] = __builtin_shufflevector(lo, hi, 0, 1, 2, 3, 4, 5, 6, 7);
    }
#pragma unroll
    for (int rf = 0; rf < 4; ++rf)
#pragma unroll
      for (int cf = 0; cf < CF; ++cf)
        acc[rf][cf] =
            __builtin_amdgcn_mfma_f32_16x16x32_bf16(af[rf], bfr[cf], acc[rf][cf], 0, 0, 0);
    __syncthreads();
  }

  float sasv[CF], sadv[CF];
#pragma unroll
  for (int cf = 0; cf < CF; ++cf) {
    int L = w * (CF * 16) + cf * 16 + c16;
    sasv[cf] = a_s[L];
    sadv[cf] = a_d[L];
  }
  // slice-major store base: subtable = w*2 + (c16>>3)
  const size_t sub = (size_t)(w * 2 + (c16 >> 3)) * (size_t)M * SF;
#pragma unroll
  for (int rf = 0; rf < 4; ++rf) {
#pragma unroll
    for (int r = 0; r < 4; ++r) {
      int n = bm + rf * 16 + q * 4 + r;
      float ps = 0.f, pd = 0.f;
      unsigned short us[CF];
#pragma unroll
      for (int cf = 0; cf < CF; ++cf) {
        float v = acc[rf][cf][r];
        us[cf] = f2bf(v);
        ps += v * sasv[cf];
        pd += v * sadv[cf];
      }
#pragma unroll
      for (int off = 1; off <= 8; off <<= 1) {
        ps += __shfl_xor(ps, off, 16);
        pd += __shfl_xor(pd, off, 16);
      }
      if (n < M) {
        if constexpr (CF == 4) {
          ushort4 u;
          u.x = us[0]; u.y = us[1]; u.z = us[2]; u.w = us[3];
          *(ushort4*)(hout + sub + (size_t)n * 32 + (c16 & 7) * 4) = u;
        } else {
          ushort2 u;
          u.x = us[0]; u.y = us[1];
          *(ushort2*)(hout + sub + (size_t)n * 16 + (c16 & 7) * 2) = u;
        }
        if (c16 == 0) {
          als[(size_t)n * 4 + w] = ps;
          ald[(size_t)n * 4 + w] = pd;
        }
      }
    }
  }
}

// ---------------- alpha precompute: normalized softmax coefficients --------
// Wave per node; lanes = 16 edge-slots x 4 heads. Pass A: ssum per head.
// Pass B: alpha[head][e] = exp(leaky(als[s]+ald[n]))*inv. CSR-ordered planes.

__global__ __launch_bounds__(256) void alpha_kernel(
    const float* __restrict__ als, const float* __restrict__ ald,
    const int* __restrict__ row_start, const int* __restrict__ csr_src,
    float* __restrict__ alpha, int E, int n_nodes) {
  int wid = threadIdx.x >> 6, lane = threadIdx.x & 63;
  int n = __builtin_amdgcn_readfirstlane(blockIdx.x * 4 + wid);
  if (n >= n_nodes) return;
  int head = lane & 3;
  int eg = lane >> 2;  // 16 edge slots
  float aldv = ald[(size_t)n * 4 + head];
  int row = __builtin_amdgcn_readfirstlane(row_start[n]);
  int end = __builtin_amdgcn_readfirstlane(row_start[n + 1]);
  float ssum = 0.f;
  for (int i = row; i < end; i += 16) {
    int e = i + eg;
    int ec = (e < end) ? e : (end - 1);
    int s = csr_src[ec];
    float x = als[(size_t)(unsigned)s * 4 + head] + aldv;
    x = fmaxf(x, 0.2f * x);
    float ex = __expf(x);
    ssum += (e < end) ? ex : 0.f;
  }
  ssum += __shfl_xor(ssum, 4, 64);
  ssum += __shfl_xor(ssum, 8, 64);
  ssum += __shfl_xor(ssum, 16, 64);
  ssum += __shfl_xor(ssum, 32, 64);
  float inv = 1.f / (ssum + 1e-16f);
  float* apl = alpha + (size_t)head * (unsigned)E;
  for (int i = row; i < end; i += 16) {
    int e = i + eg;
    if (e < end) {
      int s = csr_src[e];
      float x = als[(size_t)(unsigned)s * 4 + head] + aldv;
      x = fmaxf(x, 0.2f * x);
      apl[e] = __expf(x) * inv;
    }
  }
}

// ---------------- XCD-sliced GAT aggregation (8 nodes/wave) + BN + ELU ------
// slice = blockIdx%8 -> XCD affinity; per-XCD h working set 3.2MB/1.6MB (L2).
// Wave = 8 nodes x 8 feat-lanes; each 8-lane group serially walks its node's
// edges (uniform wave-max-degree loop, inactive lanes masked a=0, clamped
// idx). No cross-lane reduction. BN pre-folded to sc/sh.

template <int D>
__global__ __launch_bounds__(256) void gat_agg_slice(
    const unsigned short* __restrict__ h_sl,  // 8 slice-major subtables
    const float* __restrict__ alpha,          // [4][E]
    const int* __restrict__ row_start, const int* __restrict__ csr_src,
    const float* __restrict__ bnsc, const float* __restrict__ bnsh,  // [D] logical
    unsigned short* __restrict__ obf,  // D==256 out (bf16 phys rows)
    float* __restrict__ of32,          // D==128 out (f32 phys rows)
    int E, int n_nodes) {
  constexpr int SFEAT = D / 8;   // 32 | 16
  constexpr int KF = SFEAT / 8;  // feats per lane: 4 | 2
  const int sl = blockIdx.x & 7;
  const int g = blockIdx.x >> 3;
  const int wid = threadIdx.x >> 6, lane = threadIdx.x & 63;
  const int f = lane & 7;    // feat slot
  const int ng = lane >> 3;  // node sub-slot 0..7
  const int head = sl >> 1;
  const char* hb = (const char*)(h_sl + (size_t)sl * (unsigned)n_nodes * SFEAT);
  const char* cb = (const char*)csr_src;
  const char* apb = (const char*)(alpha + (size_t)head * (unsigned)E);
  const unsigned uoff = (unsigned)(f * KF * 2);  // byte off in slice row

  // folded BN constants for this lane's logical cols (independent of node)
  const int lb = (D == 256 ? head * 64 : head * 32) + (sl & 1) * 8 + f;
  float sc0 = bnsc[lb], sh0 = bnsh[lb];
  float sc1 = bnsc[lb + 16], sh1 = bnsh[lb + 16];
  float sc2 = 0.f, sh2 = 0.f, sc3 = 0.f, sh3 = 0.f;
  if constexpr (D == 256) {
    sc2 = bnsc[lb + 32]; sh2 = bnsh[lb + 32];
    sc3 = bnsc[lb + 48]; sh3 = bnsh[lb + 48];
  }

  int n = g * 32 + wid * 8 + ng;
  bool valid = n < n_nodes;
  int nc = valid ? n : (n_nodes - 1);
  int row = row_start[nc];
  int deg = row_start[nc + 1] - row;
  if (!valid) deg = 0;
  // wave-max degree (ng lives in lane bits 3..5)
  int mx = deg;
#pragma unroll
  for (int off = 8; off <= 32; off <<= 1) mx = max(mx, __shfl_xor(mx, off, 64));
  mx = __builtin_amdgcn_readfirstlane(mx);

  float acc0 = 0.f, acc1 = 0.f, acc2 = 0.f, acc3 = 0.f;
#pragma unroll 2
  for (int j = 0; j < mx; ++j) {
    bool act = j < deg;
    unsigned idx = (unsigned)(row + (act ? j : 0));
    int s = *(const int*)(cb + idx * 4u);
    float a = *(const float*)(apb + idx * 4u);
    a = act ? a : 0.f;
    if constexpr (D == 256) {
      uint2v u = *(const uint2v*)(hb + ((unsigned)s * 64u + uoff));
      acc0 += a * __uint_as_float(u.x << 16);
      acc1 += a * __uint_as_float(u.x & 0xffff0000u);
      acc2 += a * __uint_as_float(u.y << 16);
      acc3 += a * __uint_as_float(u.y & 0xffff0000u);
    } else {
      unsigned u = *(const unsigned*)(hb + ((unsigned)s * 32u + uoff));
      acc0 += a * __uint_as_float(u << 16);
      acc1 += a * __uint_as_float(u & 0xffff0000u);
    }
  }

  if (valid) {
    if constexpr (D == 256) {
      float v0 = acc0 * sc0 + sh0;
      float v1 = acc1 * sc1 + sh1;
      float v2 = acc2 * sc2 + sh2;
      float v3 = acc3 * sc3 + sh3;
      v0 = (v0 > 0.f) ? v0 : (__expf(v0) - 1.f);
      v1 = (v1 > 0.f) ? v1 : (__expf(v1) - 1.f);
      v2 = (v2 > 0.f) ? v2 : (__expf(v2) - 1.f);
      v3 = (v3 > 0.f) ? v3 : (__expf(v3) - 1.f);
      uint2v pk;
      pk.x = (unsigned)f2bf(v0) | ((unsigned)f2bf(v1) << 16);
      pk.y = (unsigned)f2bf(v2) | ((unsigned)f2bf(v3) << 16);
      __builtin_nontemporal_store(
          pk, (uint2v*)(obf + (size_t)n * 256 + sl * 32 + f * 4));
    } else {
      float v0 = acc0 * sc0 + sh0;
      float v1 = acc1 * sc1 + sh1;
      v0 = (v0 > 0.f) ? v0 : (__expf(v0) - 1.f);
      v1 = (v1 > 0.f) ? v1 : (__expf(v1) - 1.f);
      f2v v2;
      v2.x = v0; v2.y = v1;
      __builtin_nontemporal_store(
          v2, (f2v*)(of32 + (size_t)n * 128 + sl * 16 + f * 2));
    }
  }
}

// ---------------- layer-3 prep: h3 = o2 @ W3, als3/ald3 ---------------------

__global__ __launch_bounds__(256) void l3_prep_kernel(
    const float* __restrict__ o2, const float* __restrict__ W3,
    const float* __restrict__ a3s, const float* __restrict__ a3d,
    float4* __restrict__ h3p, float* __restrict__ ald3, int n_nodes) {
  __shared__ float w3s[384];
  __shared__ float sa3[6];
  for (int i = threadIdx.x; i < 384; i += 256) w3s[i] = W3[i];
  if (threadIdx.x < 3) {
    sa3[threadIdx.x] = a3s[threadIdx.x];
    sa3[3 + threadIdx.x] = a3d[threadIdx.x];
  }
  __syncthreads();
  int wid = threadIdx.x >> 6, lane = threadIdx.x & 63;
  int n = blockIdx.x * 4 + wid;
  if (n >= n_nodes) return;
  f2v v = *(const f2v*)(o2 + (size_t)n * 128 + lane * 2);  // phys cols lane*2,+1
  int hd = lane >> 4;
  int k0l = hd * 32 + (lane & 15);  // logical k of phys col lane*2
  int k1l = k0l + 16;               // logical k of phys col lane*2+1
  float p0 = v.x * w3s[k0l * 3 + 0] + v.y * w3s[k1l * 3 + 0];
  float p1 = v.x * w3s[k0l * 3 + 1] + v.y * w3s[k1l * 3 + 1];
  float p2 = v.x * w3s[k0l * 3 + 2] + v.y * w3s[k1l * 3 + 2];
#pragma unroll
  for (int off = 32; off >= 1; off >>= 1) {
    p0 += __shfl_xor(p0, off, 64);
    p1 += __shfl_xor(p1, off, 64);
    p2 += __shfl_xor(p2, off, 64);
  }
  if (lane == 0) {
    float als3 = p0 * sa3[0] + p1 * sa3[1] + p2 * sa3[2];
    float ad3 = p0 * sa3[3] + p1 * sa3[4] + p2 * sa3[5];
    h3p[n] = make_float4(p0, p1, p2, als3);
    ald3[n] = ad3;
  }
}

// ---------------- layer 3 aggregation + log_softmax -------------------------

__global__ __launch_bounds__(256) void l3_agg_kernel(const float4* __restrict__ h3p,
                                                     const float* __restrict__ ald3,
                                                     const int* __restrict__ row_start,
                                                     const int* __restrict__ csr_src,
                                                     const float* __restrict__ b3,
                                                     float* __restrict__ out, int n_nodes) {
  int wid = threadIdx.x >> 6, lane = threadIdx.x & 63;
  int n = __builtin_amdgcn_readfirstlane(blockIdx.x * 4 + wid);
  if (n >= n_nodes) return;
  float aldv = ald3[n];
  int row = __builtin_amdgcn_readfirstlane(row_start[n]);
  int end = __builtin_amdgcn_readfirstlane(row_start[n + 1]);
  const char* hp = (const char*)h3p;
  float a0 = 0.f, a1 = 0.f, a2 = 0.f, ss = 0.f;
  for (int i = row + lane; i < end; i += 64) {
    int s = csr_src[i];
    float4 hv = *(const float4*)(hp + ((unsigned)s * 16u));
    float e = hv.w + aldv;
    e = fmaxf(e, 0.2f * e);
    float ex = __expf(e);
    ss += ex;
    a0 += ex * hv.x;
    a1 += ex * hv.y;
    a2 += ex * hv.z;
  }
#pragma unroll
  for (int off = 32; off >= 1; off >>= 1) {
    a0 += __shfl_xor(a0, off, 64);
    a1 += __shfl_xor(a1, off, 64);
    a2 += __shfl_xor(a2, off, 64);
    ss += __shfl_xor(ss, off, 64);
  }
  if (lane == 0) {
    float inv = 1.f / (ss + 1e-16f);
    float o0 = a0 * inv + b3[0];
    float o1 = a1 * inv + b3[1];
    float o2 = a2 * inv + b3[2];
    float m = fmaxf(o0, fmaxf(o1, o2));
    float lse = m + logf(expf(o0 - m) + expf(o1 - m) + expf(o2 - m));
    out[n * 3 + 0] = o0 - lse;
    out[n * 3 + 1] = o1 - lse;
    out[n * 3 + 2] = o2 - lse;
  }
}

// ---------------------------------------------------------------------------

extern "C" void kernel_launch(void* const* d_in, const int* in_sizes, int n_in,
                              void* d_out, int out_size, void* d_ws, size_t ws_size,
                              hipStream_t stream) {
  const float* x   = (const float*)d_in[0];
  const int*   ei  = (const int*)d_in[1];
  const float* W1  = (const float*)d_in[2];
  const float* a1s = (const float*)d_in[3];
  const float* a1d = (const float*)d_in[4];
  const float* b1  = (const float*)d_in[5];
  const float* g1v = (const float*)d_in[6];
  const float* be1 = (const float*)d_in[7];
  const float* m1  = (const float*)d_in[8];
  const float* v1  = (const float*)d_in[9];
  const float* W2  = (const float*)d_in[10];
  const float* a2s = (const float*)d_in[11];
  const float* a2d = (const float*)d_in[12];
  const float* b2  = (const float*)d_in[13];
  const float* g2v = (const float*)d_in[14];
  const float* be2 = (const float*)d_in[15];
  const float* m2  = (const float*)d_in[16];
  const float* v2  = (const float*)d_in[17];
  const float* W3  = (const float*)d_in[18];
  const float* a3s = (const float*)d_in[19];
  const float* a3d = (const float*)d_in[20];
  const float* b3  = (const float*)d_in[21];
  float* out = (float*)d_out;

  const int N = in_sizes[0] / 128;  // 50000
  const int E = in_sizes[1] / 2;    // 850000
  const int* srcv = ei;
  const int* dstv = ei + E;

  // workspace carve-up (~73 MB), h2s LAST so alpha1 can alias + spill past it
  float* wsf  = (float*)d_ws;
  float* als1 = wsf;                   // N*4
  float* ald1 = als1 + (size_t)N * 4;
  float* als2 = ald1 + (size_t)N * 4;
  float* ald2 = als2 + (size_t)N * 4;
  float* h3p  = ald2 + (size_t)N * 4;  // N*4 (float4 rows)
  float* ald3 = h3p + (size_t)N * 4;   // N
  unsigned short* h1s   = (unsigned short*)(ald3 + N);  // N*256 (8 subtables N*32)
  unsigned short* o1_bf = h1s + (size_t)N * 256;        // N*256 row-major phys
  unsigned short* W1t   = o1_bf + (size_t)N * 256;      // 256*128
  unsigned short* W2t   = W1t + 256 * 128;              // 128*256
  int* deg       = (int*)(W2t + 128 * 256);  // N
  int* row_start = deg + N;                  // N+1
  int* cursor    = row_start + (N + 1);      // N+1
  int* csr_src   = cursor + (N + 1);         // E
  int* bsum      = csr_src + E;              // 1024
  float* bnsc1 = (float*)(bsum + 1024);      // 256
  float* bnsh1 = bnsc1 + 256;                // 256
  float* bnsc2 = bnsh1 + 256;                // 128
  float* bnsh2 = bnsc2 + 128;                // 128
  unsigned short* h2s = (unsigned short*)(bnsh2 + 128);  // N*128 (8 subtables N*16)
  // aliases (lifetimes disjoint):
  float* alpha1 = (float*)h2s;    // 4*E f32; dead before gemm2 writes h2s
  float* alpha2 = (float*)o1_bf;  // 4*E f32; o1_bf dead after gemm2 reads it
  float* o2f    = (float*)h1s;    // N*128 f32; h1s dead after agg1

  const int eb = (E + 255) / 256;
  const int nb = (N + 1023) / 1024;
  const int nodes4 = (N + 3) / 4;
  const int mblocks = (N + 63) / 64;
  const int aggblocks = ((N + 31) / 32) * 8;  // 32 nodes/block x 8 slices

  // weight conversions + BN fold
  conv_w1t_kernel<<<128, 256, 0, stream>>>(W1, W1t);
  conv_w2t_kernel<<<128, 256, 0, stream>>>(W2, W2t);
  bn_prep_kernel<<<1, 512, 0, stream>>>(b1, g1v, be1, m1, v1, b2, g2v, be2, m2, v2,
                                        bnsc1, bnsh1, bnsc2, bnsh2);

  // CSR build (shared by all 3 layers)
  hipMemsetAsync(deg, 0, (size_t)N * sizeof(int), stream);
  hist_kernel<<<eb, 256, 0, stream>>>(dstv, E, deg);
  block_sums_kernel<<<nb, 256, 0, stream>>>(deg, N, bsum);
  tiny_scan_kernel<<<1, 64, 0, stream>>>(bsum, nb);
  scan_write_kernel<<<nb, 256, 0, stream>>>(deg, N, bsum, row_start, cursor);
  scatter_kernel<<<eb, 256, 0, stream>>>(srcv, dstv, E, cursor, csr_src);

  // layer 1
  gemm_mfma<128, 256, true><<<mblocks, 256, 0, stream>>>(x, W1t, a1s, a1d, h1s, als1,
                                                         ald1, N);
  alpha_kernel<<<nodes4, 256, 0, stream>>>(als1, ald1, row_start, csr_src, alpha1, E, N);
  gat_agg_slice<256><<<aggblocks, 256, 0, stream>>>(
      h1s, alpha1, row_start, csr_src, bnsc1, bnsh1, o1_bf, nullptr, E, N);
  // layer 2
  gemm_mfma<256, 128, false><<<mblocks, 256, 0, stream>>>(o1_bf, W2t, a2s, a2d, h2s, als2,
                                                          ald2, N);
  alpha_kernel<<<nodes4, 256, 0, stream>>>(als2, ald2, row_start, csr_src, alpha2, E, N);
  gat_agg_slice<128><<<aggblocks, 256, 0, stream>>>(
      h2s, alpha2, row_start, csr_src, bnsc2, bnsh2, nullptr, o2f, E, N);
  // layer 3 prep + aggregation + log_softmax
  l3_prep_kernel<<<nodes4, 256, 0, stream>>>(o2f, W3, a3s, a3d, (float4*)h3p, ald3, N);
  l3_agg_kernel<<<nodes4, 256, 0, stream>>>((const float4*)h3p, ald3, row_start, csr_src,
                                            b3, out, N);
}